// Round 3
// baseline (236.013 us; speedup 1.0000x reference)
//
#include <hip/hip_runtime.h>
#include <math.h>

#define BN 32
#define LL 1024
#define HH 128

typedef __attribute__((ext_vector_type(8))) short short8;
typedef __attribute__((ext_vector_type(4))) float f32x4;

static const size_t SZ_BF = (size_t)BN * LL * HH * 2;  // one bf16 matrix = 8 MB

__device__ __forceinline__ ushort f2bf(float x) {
  union { float f; unsigned u; } c; c.f = x;
  unsigned r = c.u + 0x7fffu + ((c.u >> 16) & 1u);
  return (ushort)(r >> 16);
}
__device__ __forceinline__ float bf2f(ushort h) {
  union { unsigned u; float f; } c; c.u = ((unsigned)h) << 16;
  return c.f;
}
__device__ __forceinline__ short8 ld8(const ushort* p) {
  return *(const short8*)p;
}

// ---------------------------------------------------------------------------
// k_convert: f32 -> bf16 copies of a,b plus transposed bf16 copies aT,bT.
// Fused: meanb[b][d] = sum_m b[m][d]; invmean[b][d] = sum_{m:mask_b=0} a[m][d]
// grid (16 l-tiles, 32 batches, 2 which), block 256.  (unchanged from R1)
// ---------------------------------------------------------------------------
__global__ __launch_bounds__(256) void k_convert(
    const float* __restrict__ a, const float* __restrict__ b,
    const int* __restrict__ mask_b,
    ushort* __restrict__ abf, ushort* __restrict__ bbf,
    ushort* __restrict__ aT, ushort* __restrict__ bT,
    float* __restrict__ meanb, float* __restrict__ invmean) {
  int bb = blockIdx.y;
  int l0 = blockIdx.x * 64;
  int which = blockIdx.z;              // 0 -> a (->invmean), 1 -> b (->meanb)
  const float* src = which ? b : a;
  ushort* dst  = which ? bbf : abf;
  ushort* dstT = which ? bT : aT;
  float* dmean = which ? meanb : invmean;
  __shared__ __align__(16) ushort T[128][72];  // [d][l], padded
  __shared__ float accS[128];
  __shared__ float wgt[64];
  int t = threadIdx.x;
  if (t < 128) accS[t] = 0.f;
  if (t < 64)
    wgt[t] = which ? 1.0f : ((mask_b[bb * LL + l0 + t] == 0) ? 1.0f : 0.0f);
  int lrow = t >> 5;         // 0..7
  int dcol = (t & 31) * 4;   // 0..124
#pragma unroll
  for (int p = 0; p < 8; ++p) {
    int l = p * 8 + lrow;
    float4 v = *(const float4*)&src[((size_t)bb * LL + l0 + l) * HH + dcol];
    ushort4 u;
    u.x = f2bf(v.x); u.y = f2bf(v.y); u.z = f2bf(v.z); u.w = f2bf(v.w);
    *(ushort4*)&dst[((size_t)bb * LL + l0 + l) * HH + dcol] = u;
    T[dcol + 0][l] = u.x; T[dcol + 1][l] = u.y;
    T[dcol + 2][l] = u.z; T[dcol + 3][l] = u.w;
  }
  __syncthreads();
  int drow = t >> 3;        // 0..31
  int c8 = (t & 7) * 8;     // 0..56
#pragma unroll
  for (int q = 0; q < 4; ++q) {
    int d = q * 32 + drow;
    short8 val = *(const short8*)&T[d][c8];
    *(short8*)&dstT[((size_t)bb * HH + d) * LL + l0 + c8] = val;
    float s = 0.f;
#pragma unroll
    for (int j = 0; j < 8; ++j) s += wgt[c8 + j] * bf2f((ushort)val[j]);
    atomicAdd(&accS[d], s);
  }
  __syncthreads();
  if (t < 128) atomicAdd(&dmean[bb * HH + t], accS[t]);
}

// ---------------------------------------------------------------------------
// k_colsum v2: colsum[m] = sum_l exp(s[l][m]*temp + biasA[l] + biasB[m]).
// Block = 32 m (grid 32x32 = 1024 -> 4 blocks/CU). Waves split the l-sweep
// (wave w covers l in [w*256, w*256+256)).  Writes invc[b][m] (0 if sum==0).
// ---------------------------------------------------------------------------
__global__ __launch_bounds__(256, 4) void k_colsum(
    const ushort* __restrict__ abf, const ushort* __restrict__ bbf,
    const int* __restrict__ mask_a, const int* __restrict__ mask_b,
    const float* __restrict__ temp_p, float* __restrict__ invc) {
  int bb = blockIdx.y;
  int m0 = blockIdx.x * 32;
  int t = threadIdx.x;
  int w = t >> 6, lane = t & 63, l16 = lane & 15, quad = lane >> 4;
  float temp = temp_p[0];
  __shared__ float biasA[LL];
  __shared__ float csred[4][2][16];
  for (int i = t; i < LL; i += 256)
    biasA[i] = mask_a[bb * LL + i] ? 0.0f : -10000.0f;

  short8 Bm[2][4];
  float biasB[2];
#pragma unroll
  for (int mt = 0; mt < 2; ++mt) {
    int m = m0 + mt * 16 + l16;
    biasB[mt] = mask_b[bb * LL + m] ? 0.0f : -10000.0f;
#pragma unroll
    for (int k = 0; k < 4; ++k)
      Bm[mt][k] = ld8(&bbf[((size_t)bb * LL + m) * HH + k * 32 + quad * 8]);
  }
  __syncthreads();

  float cs[2] = {0.f, 0.f};
  for (int it = 0; it < 16; ++it) {
    int lbase = w * 256 + it * 16;
    short8 Al[4];
    const ushort* arow = &abf[((size_t)bb * LL + lbase + l16) * HH];
#pragma unroll
    for (int k = 0; k < 4; ++k) Al[k] = ld8(&arow[k * 32 + quad * 8]);
#pragma unroll
    for (int mt = 0; mt < 2; ++mt) {
      f32x4 sacc = {0.f, 0.f, 0.f, 0.f};
#pragma unroll
      for (int k = 0; k < 4; ++k)
        sacc = __builtin_amdgcn_mfma_f32_16x16x32_bf16(Al[k], Bm[mt][k], sacc, 0, 0, 0);
#pragma unroll
      for (int r = 0; r < 4; ++r) {
        int l = lbase + quad * 4 + r;   // D row = l; col = m = m0+mt*16+l16
        cs[mt] += __expf(sacc[r] * temp + biasA[l] + biasB[mt]);
      }
    }
  }
#pragma unroll
  for (int mt = 0; mt < 2; ++mt) {
    cs[mt] += __shfl_xor(cs[mt], 16);
    cs[mt] += __shfl_xor(cs[mt], 32);
  }
  if (lane < 16) {
#pragma unroll
    for (int mt = 0; mt < 2; ++mt) csred[w][mt][l16] = cs[mt];
  }
  __syncthreads();
  if (t < 32) {
    float s = csred[0][t >> 4][t & 15] + csred[1][t >> 4][t & 15] +
              csred[2][t >> 4][t & 15] + csred[3][t >> 4][t & 15];
    invc[bb * LL + m0 + t] = s > 0.f ? 1.0f / s : 0.0f;
  }
}

// ---------------------------------------------------------------------------
// k_scale: aT[d][m] *= invc[m]  (in place, elementwise; aT becomes aS).
// grid 2048, block 256: one ushort8 per thread.
// ---------------------------------------------------------------------------
__global__ __launch_bounds__(256) void k_scale(
    ushort* __restrict__ aT, const float* __restrict__ invc) {
  size_t base = ((size_t)blockIdx.x * 256 + threadIdx.x) * 8;
  int b = (int)(base >> 17);          // 128*1024 elems per batch
  int m = (int)(base & (LL - 1));
  short8 v = *(short8*)&aT[base];
  float4 i0 = *(const float4*)&invc[b * LL + m];
  float4 i1 = *(const float4*)&invc[b * LL + m + 4];
  short8 o;
  o[0] = (short)f2bf(bf2f((ushort)v[0]) * i0.x);
  o[1] = (short)f2bf(bf2f((ushort)v[1]) * i0.y);
  o[2] = (short)f2bf(bf2f((ushort)v[2]) * i0.z);
  o[3] = (short)f2bf(bf2f((ushort)v[3]) * i0.w);
  o[4] = (short)f2bf(bf2f((ushort)v[4]) * i1.x);
  o[5] = (short)f2bf(bf2f((ushort)v[5]) * i1.y);
  o[6] = (short)f2bf(bf2f((ushort)v[6]) * i1.z);
  o[7] = (short)f2bf(bf2f((ushort)v[7]) * i1.w);
  *(short8*)&aT[base] = o;
}

// ---------------------------------------------------------------------------
// k_features v3: block = 32 l-rows (grid 32x32 = 1024 blocks).
//   S-phase: wave w computes S'[m-slice w (16m)][all 32 l]; Pa = bf16(e) -> LDS
//            (double-buffered, ONE barrier/iter).  No Pb: feature_b uses
//            pre-scaled aS so both F-matmuls share the Pa operand.
//   F-phase: wave w owns d-slice w*32: accA += Pa @ bT, accB += Pa @ aS,
//            accR += Pa @ ones  (rowsum on the MFMA pipe, lane-aligned with
//            the epilogue -> zero cross-wave reduction).
// Epilogue: fa = rowsum>0 ? accA/rowsum : mean(b); fb = accB + invmean_a/1024.
// ---------------------------------------------------------------------------
__global__ __launch_bounds__(256, 3) void k_features(
    const ushort* __restrict__ abf, const ushort* __restrict__ bbf,
    const ushort* __restrict__ aS, const ushort* __restrict__ bT,
    const int* __restrict__ mask_a, const int* __restrict__ mask_b,
    const float* __restrict__ temp_p, const float* __restrict__ meanb,
    const float* __restrict__ invmean, float* __restrict__ out) {
  int bb = blockIdx.y;
  int l0 = blockIdx.x * 32;
  int t = threadIdx.x;
  int w = t >> 6, lane = t & 63, l16 = lane & 15, quad = lane >> 4;
  float temp = temp_p[0];

  __shared__ float biasBs[LL];                     // 4 KB
  __shared__ __align__(16) ushort Pa[2][32 * 72];  // 9.2 KB double-buffered

  for (int i = t; i < LL; i += 256)
    biasBs[i] = mask_b[bb * LL + i] ? 0.0f : -10000.0f;

  float biasA_lt[2];
  short8 Afix[2][4];   // abf rows l0..l0+31 as B-operands
#pragma unroll
  for (int lt = 0; lt < 2; ++lt) {
    int l = l0 + lt * 16 + l16;
    biasA_lt[lt] = mask_a[bb * LL + l] ? 0.0f : -10000.0f;
#pragma unroll
    for (int k = 0; k < 4; ++k)
      Afix[lt][k] = ld8(&abf[((size_t)bb * LL + l) * HH + k * 32 + quad * 8]);
  }
  short8 Bones;
#pragma unroll
  for (int j = 0; j < 8; ++j) Bones[j] = (short)0x3F80;  // bf16 1.0

  f32x4 accA[2][2], accB[2][2], accR[2];
  f32x4 zero = {0.f, 0.f, 0.f, 0.f};
#pragma unroll
  for (int lt = 0; lt < 2; ++lt) {
    accR[lt] = zero;
#pragma unroll
    for (int dt = 0; dt < 2; ++dt) { accA[lt][dt] = zero; accB[lt][dt] = zero; }
  }
  __syncthreads();   // biasBs ready

  int buf = 0;
  for (int m0 = 0; m0 < LL; m0 += 64) {
    // global loads for this iter
    short8 Am[4];
    const ushort* brow = &bbf[((size_t)bb * LL + m0 + w * 16 + l16) * HH];
#pragma unroll
    for (int k = 0; k < 4; ++k) Am[k] = ld8(&brow[k * 32 + quad * 8]);
    short8 Bb[2][2], Bs[2][2];
#pragma unroll
    for (int dt = 0; dt < 2; ++dt) {
      size_t drow = (size_t)bb * HH + w * 32 + dt * 16 + l16;
      const ushort* btrow = &bT[drow * LL + m0];
      const ushort* asrow = &aS[drow * LL + m0];
#pragma unroll
      for (int ks = 0; ks < 2; ++ks) {
        Bb[dt][ks] = ld8(&btrow[ks * 32 + quad * 8]);
        Bs[dt][ks] = ld8(&asrow[ks * 32 + quad * 8]);
      }
    }
    float bB[4];
#pragma unroll
    for (int r = 0; r < 4; ++r) bB[r] = biasBs[m0 + w * 16 + quad * 4 + r];

    // S-phase: D[m = w*16+quad*4+r][l = lt*16+l16]
    ushort* pa = &Pa[buf][0];
#pragma unroll
    for (int lt = 0; lt < 2; ++lt) {
      f32x4 sacc = zero;
#pragma unroll
      for (int k = 0; k < 4; ++k)
        sacc = __builtin_amdgcn_mfma_f32_16x16x32_bf16(Am[k], Afix[lt][k], sacc, 0, 0, 0);
      ushort pav[4];
#pragma unroll
      for (int r = 0; r < 4; ++r)
        pav[r] = f2bf(__expf(sacc[r] * temp + biasA_lt[lt] + bB[r]));
      uint2 ka;
      ka.x = (uint)pav[0] | ((uint)pav[1] << 16);
      ka.y = (uint)pav[2] | ((uint)pav[3] << 16);
      *(uint2*)&pa[(lt * 16 + l16) * 72 + w * 16 + quad * 4] = ka;
    }
    __syncthreads();   // P[buf] complete (prev buf unused now -> 1 barrier ok)

    // F-phase: D[l = lt*16+quad*4+r][d = w*32+dt*16+l16]
#pragma unroll
    for (int lt = 0; lt < 2; ++lt) {
#pragma unroll
      for (int ks = 0; ks < 2; ++ks) {
        short8 PaF = *(const short8*)&pa[(lt * 16 + l16) * 72 + ks * 32 + quad * 8];
        accR[lt] = __builtin_amdgcn_mfma_f32_16x16x32_bf16(PaF, Bones, accR[lt], 0, 0, 0);
#pragma unroll
        for (int dt = 0; dt < 2; ++dt) {
          accA[lt][dt] = __builtin_amdgcn_mfma_f32_16x16x32_bf16(PaF, Bb[dt][ks], accA[lt][dt], 0, 0, 0);
          accB[lt][dt] = __builtin_amdgcn_mfma_f32_16x16x32_bf16(PaF, Bs[dt][ks], accB[lt][dt], 0, 0, 0);
        }
      }
    }
    buf ^= 1;
  }

  // epilogue — accR already lane-aligned (row l in slot r), no reduction needed
  float* outA = out;
  float* outB = out + (size_t)BN * LL * HH;
#pragma unroll
  for (int dt = 0; dt < 2; ++dt) {
    int d = w * 32 + dt * 16 + l16;
    float mb = meanb[bb * HH + d] * (1.0f / 1024.0f);
    float im = invmean[bb * HH + d] * (1.0f / 1024.0f);
#pragma unroll
    for (int lt = 0; lt < 2; ++lt) {
#pragma unroll
      for (int r = 0; r < 4; ++r) {
        int l = l0 + lt * 16 + quad * 4 + r;
        float rsv = accR[lt][r];
        float fa = (rsv > 0.f) ? accA[lt][dt][r] / rsv : mb;
        float fb = accB[lt][dt][r] + im;
        outA[((size_t)bb * LL + l) * HH + d] = fa;
        outB[((size_t)bb * LL + l) * HH + d] = fb;
      }
    }
  }
}

// ---------------------------------------------------------------------------
extern "C" void kernel_launch(void* const* d_in, const int* in_sizes, int n_in,
                              void* d_out, int out_size, void* d_ws, size_t ws_size,
                              hipStream_t stream) {
  const float* a = (const float*)d_in[0];
  const float* b = (const float*)d_in[1];
  const int* mask_a = (const int*)d_in[2];
  const int* mask_b = (const int*)d_in[3];
  const float* temp = (const float*)d_in[4];
  float* out = (float*)d_out;

  char* wsb = (char*)d_ws;
  ushort* abf = (ushort*)(wsb + 0 * SZ_BF);
  ushort* bbf = (ushort*)(wsb + 1 * SZ_BF);
  ushort* aT  = (ushort*)(wsb + 2 * SZ_BF);   // becomes aS after k_scale
  ushort* bT  = (ushort*)(wsb + 3 * SZ_BF);
  float* invc = (float*)(wsb + 4 * SZ_BF);
  float* meanb   = invc + (size_t)BN * LL;
  float* invmean = meanb + BN * HH;

  hipMemsetAsync(meanb, 0, 2 * BN * HH * sizeof(float), stream);
  k_convert<<<dim3(16, 32, 2), 256, 0, stream>>>(a, b, mask_b, abf, bbf, aT, bT,
                                                 meanb, invmean);
  k_colsum<<<dim3(32, 32), 256, 0, stream>>>(abf, bbf, mask_a, mask_b, temp, invc);
  k_scale<<<dim3(2048), 256, 0, stream>>>(aT, invc);
  k_features<<<dim3(32, 32), 256, 0, stream>>>(abf, bbf, aT, bT, mask_a, mask_b,
                                               temp, meanb, invmean, out);
  (void)in_sizes; (void)n_in; (void)out_size; (void)ws_size;
}

// Round 7
// 193.423 us; speedup vs baseline: 1.2202x; 1.2202x over previous
//
#include <hip/hip_runtime.h>
#include <math.h>

#define BN 32
#define LL 1024
#define HH 128

typedef __attribute__((ext_vector_type(8))) short short8;
typedef __attribute__((ext_vector_type(4))) float f32x4;

static const size_t SZ_BF = (size_t)BN * LL * HH * 2;  // one bf16 matrix = 8 MB

__device__ __forceinline__ ushort f2bf(float x) {
  union { float f; unsigned u; } c; c.f = x;
  unsigned r = c.u + 0x7fffu + ((c.u >> 16) & 1u);
  return (ushort)(r >> 16);
}
__device__ __forceinline__ float bf2f(ushort h) {
  union { unsigned u; float f; } c; c.u = ((unsigned)h) << 16;
  return c.f;
}
__device__ __forceinline__ short8 ld8(const ushort* p) {
  return *(const short8*)p;
}

// ---------------------------------------------------------------------------
// k_convert: f32 -> bf16 copies of a,b plus transposed bf16 copies aT,bT.
// Fused: meanb[b][d] = sum_m b[m][d]; invmean[b][d] = sum_{m:mask_b=0} a[m][d]
// grid (16 l-tiles, 32 batches, 2 which), block 256.  (streaming; no reuse ->
// XCD placement irrelevant here)
// ---------------------------------------------------------------------------
__global__ __launch_bounds__(256) void k_convert(
    const float* __restrict__ a, const float* __restrict__ b,
    const int* __restrict__ mask_b,
    ushort* __restrict__ abf, ushort* __restrict__ bbf,
    ushort* __restrict__ aT, ushort* __restrict__ bT,
    float* __restrict__ meanb, float* __restrict__ invmean) {
  int bb = blockIdx.y;
  int l0 = blockIdx.x * 64;
  int which = blockIdx.z;              // 0 -> a (->invmean), 1 -> b (->meanb)
  const float* src = which ? b : a;
  ushort* dst  = which ? bbf : abf;
  ushort* dstT = which ? bT : aT;
  float* dmean = which ? meanb : invmean;
  __shared__ __align__(16) ushort T[128][72];  // [d][l], padded
  __shared__ float accS[128];
  __shared__ float wgt[64];
  int t = threadIdx.x;
  if (t < 128) accS[t] = 0.f;
  if (t < 64)
    wgt[t] = which ? 1.0f : ((mask_b[bb * LL + l0 + t] == 0) ? 1.0f : 0.0f);
  int lrow = t >> 5;         // 0..7
  int dcol = (t & 31) * 4;   // 0..124
#pragma unroll
  for (int p = 0; p < 8; ++p) {
    int l = p * 8 + lrow;
    float4 v = *(const float4*)&src[((size_t)bb * LL + l0 + l) * HH + dcol];
    ushort4 u;
    u.x = f2bf(v.x); u.y = f2bf(v.y); u.z = f2bf(v.z); u.w = f2bf(v.w);
    *(ushort4*)&dst[((size_t)bb * LL + l0 + l) * HH + dcol] = u;
    T[dcol + 0][l] = u.x; T[dcol + 1][l] = u.y;
    T[dcol + 2][l] = u.z; T[dcol + 3][l] = u.w;
  }
  __syncthreads();
  int drow = t >> 3;        // 0..31
  int c8 = (t & 7) * 8;     // 0..56
#pragma unroll
  for (int q = 0; q < 4; ++q) {
    int d = q * 32 + drow;
    short8 val = *(const short8*)&T[d][c8];
    *(short8*)&dstT[((size_t)bb * HH + d) * LL + l0 + c8] = val;
    float s = 0.f;
#pragma unroll
    for (int j = 0; j < 8; ++j) s += wgt[c8 + j] * bf2f((ushort)val[j]);
    atomicAdd(&accS[d], s);
  }
  __syncthreads();
  if (t < 128) atomicAdd(&dmean[bb * HH + t], accS[t]);
}

// ---------------------------------------------------------------------------
// k_colsum v3: colsum[m] = sum_l exp(s[l][m]*temp + biasA[l] + biasB[m]).
// 1-D grid 1024, bb = wg&31 (XCD = wg%8 = bb%8 -> all blocks of a batch on one
// XCD, abf stays L2-resident). Block = 32 m; waves split the l-sweep; Al
// prefetched one iter ahead (wrap-indexed).  FUSED: scales aT[d][m0..m0+31]
// in place by inv_colsum (aT becomes aS), pre-warming it into this XCD's L2.
// ---------------------------------------------------------------------------
__global__ __launch_bounds__(256, 4) void k_colsum(
    const ushort* __restrict__ abf, const ushort* __restrict__ bbf,
    const int* __restrict__ mask_a, const int* __restrict__ mask_b,
    const float* __restrict__ temp_p, ushort* __restrict__ aT) {
  int wg = blockIdx.x;
  int bb = wg & 31;
  int m0 = (wg >> 5) * 32;
  int t = threadIdx.x;
  int w = t >> 6, lane = t & 63, l16 = lane & 15, quad = lane >> 4;
  float temp = temp_p[0];
  __shared__ float biasA[LL];
  __shared__ float csred[4][2][16];
  __shared__ float invs[32];
  for (int i = t; i < LL; i += 256)
    biasA[i] = mask_a[bb * LL + i] ? 0.0f : -10000.0f;

  short8 Bm[2][4];
  float biasB[2];
#pragma unroll
  for (int mt = 0; mt < 2; ++mt) {
    int m = m0 + mt * 16 + l16;
    biasB[mt] = mask_b[bb * LL + m] ? 0.0f : -10000.0f;
#pragma unroll
    for (int k = 0; k < 4; ++k)
      Bm[mt][k] = ld8(&bbf[((size_t)bb * LL + m) * HH + k * 32 + quad * 8]);
  }
  __syncthreads();

  // prologue load for it=0
  short8 Al[4];
  {
    const ushort* arow = &abf[((size_t)bb * LL + w * 256 + l16) * HH];
#pragma unroll
    for (int k = 0; k < 4; ++k) Al[k] = ld8(&arow[k * 32 + quad * 8]);
  }
  float cs[2] = {0.f, 0.f};
  for (int it = 0; it < 16; ++it) {
    int lbase = w * 256 + it * 16;
    // prefetch next iter's A-frags (wrap at end; redundant last load is cheap)
    short8 AlN[4];
    {
      int itn = (it + 1) & 15;
      const ushort* arow = &abf[((size_t)bb * LL + w * 256 + itn * 16 + l16) * HH];
#pragma unroll
      for (int k = 0; k < 4; ++k) AlN[k] = ld8(&arow[k * 32 + quad * 8]);
    }
#pragma unroll
    for (int mt = 0; mt < 2; ++mt) {
      f32x4 sacc = {0.f, 0.f, 0.f, 0.f};
#pragma unroll
      for (int k = 0; k < 4; ++k)
        sacc = __builtin_amdgcn_mfma_f32_16x16x32_bf16(Al[k], Bm[mt][k], sacc, 0, 0, 0);
#pragma unroll
      for (int r = 0; r < 4; ++r) {
        int l = lbase + quad * 4 + r;   // D row = l; col = m = m0+mt*16+l16
        cs[mt] += __expf(sacc[r] * temp + biasA[l] + biasB[mt]);
      }
    }
#pragma unroll
    for (int k = 0; k < 4; ++k) Al[k] = AlN[k];
  }
#pragma unroll
  for (int mt = 0; mt < 2; ++mt) {
    cs[mt] += __shfl_xor(cs[mt], 16);
    cs[mt] += __shfl_xor(cs[mt], 32);
  }
  if (lane < 16) {
#pragma unroll
    for (int mt = 0; mt < 2; ++mt) csred[w][mt][l16] = cs[mt];
  }
  __syncthreads();
  if (t < 32) {
    float s = csred[0][t >> 4][t & 15] + csred[1][t >> 4][t & 15] +
              csred[2][t >> 4][t & 15] + csred[3][t >> 4][t & 15];
    invs[t] = s > 0.f ? 1.0f / s : 0.0f;
  }
  __syncthreads();
  // scale aT columns [m0, m0+32) in place (aT -> aS)
  {
    int ml = t & 31;
    float iv = invs[ml];
    for (int d = t >> 5; d < HH; d += 8) {
      size_t idx = ((size_t)bb * HH + d) * LL + m0 + ml;
      aT[idx] = f2bf(bf2f(aT[idx]) * iv);
    }
  }
}

// ---------------------------------------------------------------------------
// k_features v4: 64 l-rows/block, 1-D grid 512, bb = wg&31 (XCD = bb%8 ->
// hot set bbf+bT+aS of 4 batches = 3 MB fits the XCD's 4 MB L2).
//   S-phase: wave w computes S'[m-slice w (16m)][all 64 l]; Pa = bf16(e) ->
//            shared LDS [l][m] (double-buffered, ONE barrier/iter); rowsum
//            accumulated in-register from the rounded Pa values.
//   F-phase: wave w owns d-slice w*32: accA += Pa @ bT, accB += Pa @ aS
//            (aS pre-scaled by inv_colsum -> single shared Pa operand).
//   Am (bbf A-frags) prefetched one iter ahead, wrap-indexed.
// Epilogue: fa = rowsum>0 ? accA/rowsum : mean(b); fb = accB + invmean_a/1024.
// ---------------------------------------------------------------------------
__global__ __launch_bounds__(256, 2) void k_features(
    const ushort* __restrict__ abf, const ushort* __restrict__ bbf,
    const ushort* __restrict__ aS, const ushort* __restrict__ bT,
    const int* __restrict__ mask_a, const int* __restrict__ mask_b,
    const float* __restrict__ temp_p, const float* __restrict__ meanb,
    const float* __restrict__ invmean, float* __restrict__ out) {
  int wg = blockIdx.x;
  int bb = wg & 31;
  int l0 = (wg >> 5) * 64;
  int t = threadIdx.x;
  int w = t >> 6, lane = t & 63, l16 = lane & 15, quad = lane >> 4;
  float temp = temp_p[0];

  __shared__ float biasBs[LL];                     // 4 KB
  __shared__ __align__(16) ushort Pa[2][64 * 72];  // 18.4 KB double-buffered
  __shared__ float rspart[4][64];
  __shared__ float rsfin[64];

  for (int i = t; i < LL; i += 256)
    biasBs[i] = mask_b[bb * LL + i] ? 0.0f : -10000.0f;

  float biasA_lt[4];
  short8 Afix[4][4];   // abf rows l0..l0+63 as B-operands (64 VGPRs)
#pragma unroll
  for (int lt = 0; lt < 4; ++lt) {
    int l = l0 + lt * 16 + l16;
    biasA_lt[lt] = mask_a[bb * LL + l] ? 0.0f : -10000.0f;
#pragma unroll
    for (int k = 0; k < 4; ++k)
      Afix[lt][k] = ld8(&abf[((size_t)bb * LL + l) * HH + k * 32 + quad * 8]);
  }

  f32x4 accA[4][2], accB[4][2];
  f32x4 zero = {0.f, 0.f, 0.f, 0.f};
#pragma unroll
  for (int lt = 0; lt < 4; ++lt)
#pragma unroll
    for (int dt = 0; dt < 2; ++dt) { accA[lt][dt] = zero; accB[lt][dt] = zero; }
  float rs_lt[4] = {0.f, 0.f, 0.f, 0.f};
  __syncthreads();   // biasBs ready

  // prologue: Am for iter 0
  short8 Am[4];
  {
    const ushort* brow = &bbf[((size_t)bb * LL + w * 16 + l16) * HH];
#pragma unroll
    for (int k = 0; k < 4; ++k) Am[k] = ld8(&brow[k * 32 + quad * 8]);
  }

  int buf = 0;
  for (int m0 = 0; m0 < LL; m0 += 64) {
    // F-phase operands for THIS iter (consumed after barrier; latency hidden
    // by S-phase + barrier)
    short8 Bb[2][2], Bs[2][2];
#pragma unroll
    for (int dt = 0; dt < 2; ++dt) {
      size_t drow = (size_t)bb * HH + w * 32 + dt * 16 + l16;
      const ushort* btrow = &bT[drow * LL + m0];
      const ushort* asrow = &aS[drow * LL + m0];
#pragma unroll
      for (int ks = 0; ks < 2; ++ks) {
        Bb[dt][ks] = ld8(&btrow[ks * 32 + quad * 8]);
        Bs[dt][ks] = ld8(&asrow[ks * 32 + quad * 8]);
      }
    }
    float bB[4];
#pragma unroll
    for (int r = 0; r < 4; ++r) bB[r] = biasBs[m0 + w * 16 + quad * 4 + r];

    // S-phase: D[m = w*16+quad*4+r][l = lt*16+l16]
    ushort* pa = &Pa[buf][0];
#pragma unroll
    for (int lt = 0; lt < 4; ++lt) {
      f32x4 sacc = zero;
#pragma unroll
      for (int k = 0; k < 4; ++k)
        sacc = __builtin_amdgcn_mfma_f32_16x16x32_bf16(Am[k], Afix[lt][k], sacc, 0, 0, 0);
      ushort pav[4];
#pragma unroll
      for (int r = 0; r < 4; ++r) {
        pav[r] = f2bf(__expf(sacc[r] * temp + biasA_lt[lt] + bB[r]));
        rs_lt[lt] += bf2f(pav[r]);     // rounded value -> cancels in fa=acc/rs
      }
      uint2 ka;
      ka.x = (uint)pav[0] | ((uint)pav[1] << 16);
      ka.y = (uint)pav[2] | ((uint)pav[3] << 16);
      *(uint2*)&pa[(lt * 16 + l16) * 72 + w * 16 + quad * 4] = ka;
    }

    // prefetch Am for next iter (wrap-indexed -> branchless)
    {
      int mn = (m0 + 64) & (LL - 1);
      const ushort* brow = &bbf[((size_t)bb * LL + mn + w * 16 + l16) * HH];
#pragma unroll
      for (int k = 0; k < 4; ++k) Am[k] = ld8(&brow[k * 32 + quad * 8]);
    }

    __syncthreads();   // P[buf] complete (prev buf unused now)

    // F-phase: D[l = lt*16+quad*4+r][d = w*32+dt*16+l16]
#pragma unroll
    for (int lt = 0; lt < 4; ++lt) {
#pragma unroll
      for (int ks = 0; ks < 2; ++ks) {
        short8 PaF = *(const short8*)&pa[(lt * 16 + l16) * 72 + ks * 32 + quad * 8];
#pragma unroll
        for (int dt = 0; dt < 2; ++dt) {
          accA[lt][dt] = __builtin_amdgcn_mfma_f32_16x16x32_bf16(PaF, Bb[dt][ks], accA[lt][dt], 0, 0, 0);
          accB[lt][dt] = __builtin_amdgcn_mfma_f32_16x16x32_bf16(PaF, Bs[dt][ks], accB[lt][dt], 0, 0, 0);
        }
      }
    }
    buf ^= 1;
  }

  // rowsum cross-wave reduce
#pragma unroll
  for (int lt = 0; lt < 4; ++lt) {
    rs_lt[lt] += __shfl_xor(rs_lt[lt], 16);
    rs_lt[lt] += __shfl_xor(rs_lt[lt], 32);
  }
  if (lane < 16) {
#pragma unroll
    for (int lt = 0; lt < 4; ++lt) rspart[w][lt * 16 + l16] = rs_lt[lt];
  }
  __syncthreads();
  if (t < 64)
    rsfin[t] = rspart[0][t] + rspart[1][t] + rspart[2][t] + rspart[3][t];
  __syncthreads();

  // epilogue
  float* outA = out;
  float* outB = out + (size_t)BN * LL * HH;
#pragma unroll
  for (int dt = 0; dt < 2; ++dt) {
    int d = w * 32 + dt * 16 + l16;
    float mb = meanb[bb * HH + d] * (1.0f / 1024.0f);
    float im = invmean[bb * HH + d] * (1.0f / 1024.0f);
#pragma unroll
    for (int lt = 0; lt < 4; ++lt) {
#pragma unroll
      for (int r = 0; r < 4; ++r) {
        int l = lt * 16 + quad * 4 + r;
        float rsv = rsfin[l];
        float fa = (rsv > 0.f) ? accA[lt][dt][r] / rsv : mb;
        float fb = accB[lt][dt][r] + im;
        outA[((size_t)bb * LL + l0 + l) * HH + d] = fa;
        outB[((size_t)bb * LL + l0 + l) * HH + d] = fb;
      }
    }
  }
}

// ---------------------------------------------------------------------------
extern "C" void kernel_launch(void* const* d_in, const int* in_sizes, int n_in,
                              void* d_out, int out_size, void* d_ws, size_t ws_size,
                              hipStream_t stream) {
  const float* a = (const float*)d_in[0];
  const float* b = (const float*)d_in[1];
  const int* mask_a = (const int*)d_in[2];
  const int* mask_b = (const int*)d_in[3];
  const float* temp = (const float*)d_in[4];
  float* out = (float*)d_out;

  char* wsb = (char*)d_ws;
  ushort* abf = (ushort*)(wsb + 0 * SZ_BF);
  ushort* bbf = (ushort*)(wsb + 1 * SZ_BF);
  ushort* aT  = (ushort*)(wsb + 2 * SZ_BF);   // becomes aS inside k_colsum
  ushort* bT  = (ushort*)(wsb + 3 * SZ_BF);
  float* meanb   = (float*)(wsb + 4 * SZ_BF);
  float* invmean = meanb + BN * HH;

  hipMemsetAsync(meanb, 0, 2 * BN * HH * sizeof(float), stream);
  k_convert<<<dim3(16, 32, 2), 256, 0, stream>>>(a, b, mask_b, abf, bbf, aT, bT,
                                                 meanb, invmean);
  k_colsum<<<dim3(1024), 256, 0, stream>>>(abf, bbf, mask_a, mask_b, temp, aT);
  k_features<<<dim3(512), 256, 0, stream>>>(abf, bbf, aT, bT, mask_a, mask_b,
                                            temp, meanb, invmean, out);
  (void)in_sizes; (void)n_in; (void)out_size; (void)ws_size;
}